// Round 1
// baseline (10.973 us; speedup 1.0000x reference)
//
#include <hip/hip_runtime.h>

// Problem constants (from reference): B=64, S=512, H=1024
constexpr int B_ = 64;
constexpr int S_ = 512;
constexpr int H_ = 1024;
constexpr int E1S_ = 30522, E1E_ = 30523, E2S_ = 30524, E2E_ = 30525;

// One block per batch row. 256 threads; thread t owns h = 4t..4t+3 (float4).
__global__ __launch_bounds__(256)
void relcls_kernel(const int* __restrict__ ids,
                   const float* __restrict__ seq,   // [B,S,H] f32
                   const float* __restrict__ W,     // [3H] f32
                   const float* __restrict__ bias,  // [1] f32
                   float* __restrict__ out)         // [B] f32
{
    const int b   = blockIdx.x;
    const int tid = threadIdx.x;

    __shared__ int spos[4];     // first occurrence of E1S,E1E,E2S,E2E (S_ = not found)
    __shared__ float wpart[4];  // per-wave partials

    if (tid < 4) spos[tid] = S_;
    __syncthreads();

    // --- scan token ids for marker positions (first occurrence == argmax) ---
    const int* idrow = ids + (size_t)b * S_;
    for (int p = tid; p < S_; p += 256) {
        int t = idrow[p];
        if (t >= E1S_ && t <= E2E_) {
            atomicMin(&spos[t - E1S_], p);
        }
    }
    __syncthreads();

    const int p_s1 = spos[0], p_e1 = spos[1], p_s2 = spos[2], p_e2 = spos[3];

    // reference semantics: found = s_hit.any & e_hit.any; start=first(S)+1; end=first(E)
    const bool f1 = (p_s1 < S_) && (p_e1 < S_);
    const int  st1 = p_s1 + 1, en1 = p_e1;
    const int  cnt1 = f1 ? max(en1 - st1, 0) : 0;

    const bool f2 = (p_s2 < S_) && (p_e2 < S_);
    const int  st2 = p_s2 + 1, en2 = p_e2;
    const int  cnt2 = f2 ? max(en2 - st2, 0) : 0;

    // --- fused pool + dot ---
    const int h0 = tid * 4;
    const float* seqb = seq + (size_t)b * S_ * H_;

    const float4 w0 = *(const float4*)(W + h0);
    const float4 w1 = *(const float4*)(W + H_ + h0);
    const float4 w2 = *(const float4*)(W + 2 * H_ + h0);

    // CLS row (position 0)
    const float4 c = *(const float4*)(seqb + h0);
    float acc = c.x * w0.x + c.y * w0.y + c.z * w0.z + c.w * w0.w;

    if (cnt1 > 0) {
        float4 s = {0.f, 0.f, 0.f, 0.f};
        for (int p = st1; p < en1; ++p) {
            const float4 v = *(const float4*)(seqb + (size_t)p * H_ + h0);
            s.x += v.x; s.y += v.y; s.z += v.z; s.w += v.w;
        }
        const float inv = 1.0f / (float)cnt1;
        acc += (s.x * w1.x + s.y * w1.y + s.z * w1.z + s.w * w1.w) * inv;
    }
    if (cnt2 > 0) {
        float4 s = {0.f, 0.f, 0.f, 0.f};
        for (int p = st2; p < en2; ++p) {
            const float4 v = *(const float4*)(seqb + (size_t)p * H_ + h0);
            s.x += v.x; s.y += v.y; s.z += v.z; s.w += v.w;
        }
        const float inv = 1.0f / (float)cnt2;
        acc += (s.x * w2.x + s.y * w2.y + s.z * w2.z + s.w * w2.w) * inv;
    }

    // --- block reduction: 64-lane wave shuffle, then 4 wave partials ---
    #pragma unroll
    for (int off = 32; off > 0; off >>= 1)
        acc += __shfl_down(acc, off, 64);
    if ((tid & 63) == 0) wpart[tid >> 6] = acc;
    __syncthreads();
    if (tid == 0) {
        out[b] = wpart[0] + wpart[1] + wpart[2] + wpart[3] + bias[0];
    }
}

extern "C" void kernel_launch(void* const* d_in, const int* in_sizes, int n_in,
                              void* d_out, int out_size, void* d_ws, size_t ws_size,
                              hipStream_t stream)
{
    const int*   ids  = (const int*)d_in[0];    // input_ids [B,S]
    // d_in[1] = attention_mask (unused by reference)
    const float* seq  = (const float*)d_in[2];  // sequence_output [B,S,H]
    const float* W    = (const float*)d_in[3];  // [3H,1]
    const float* bias = (const float*)d_in[4];  // [1]
    float* out = (float*)d_out;                 // [B]

    relcls_kernel<<<B_, 256, 0, stream>>>(ids, seq, W, bias, out);
}

// Round 2
// 9.432 us; speedup vs baseline: 1.1634x; 1.1634x over previous
//
#include <hip/hip_runtime.h>

// Problem constants: B=64, S=512, H=1024
constexpr int B_ = 64;
constexpr int S_ = 512;
constexpr int H_ = 1024;
constexpr int E1S_ = 30522, E2E_ = 30525;

constexpr int NSLICE    = 4;               // position slices (tid >> 8)
constexpr int MAXROWS   = 40;              // 1 cls + 19 + 19, rounded up to multiple of NSLICE
constexpr int PER_SLICE = MAXROWS / NSLICE; // 10 fully-unrolled iterations

// One block per batch row. 1024 threads = 256 h-threads × 4 slices.
__global__ __launch_bounds__(1024)
void relcls_kernel(const int* __restrict__ ids,
                   const float* __restrict__ seq,   // [B,S,H] f32
                   const float* __restrict__ W,     // [3H] f32
                   const float* __restrict__ bias,  // [1] f32
                   float* __restrict__ out)         // [B] f32
{
    const int b       = blockIdx.x;
    const int tid     = threadIdx.x;
    const int hthread = tid & 255;   // owns h = 4*hthread .. +3
    const int slice   = tid >> 8;    // 0..3, wave-uniform

    __shared__ int   spos[4];        // first occurrence of E1S,E1E,E2S,E2E
    __shared__ float wpart[16];      // per-wave partials

    if (tid < 4) spos[tid] = S_;
    __syncthreads();

    // --- marker scan: 512 threads, one position each ---
    const int* idrow = ids + (size_t)b * S_;
    if (tid < S_) {
        const int t = idrow[tid];
        if (t >= E1S_ && t <= E2E_) atomicMin(&spos[t - E1S_], tid);
    }
    __syncthreads();

    const int p_s1 = spos[0], p_e1 = spos[1], p_s2 = spos[2], p_e2 = spos[3];

    // reference: found = any(S)&any(E); start=first(S)+1; end=first(E); cnt=end-start (>=0)
    const bool f1  = (p_s1 < S_) && (p_e1 < S_);
    const int  st1 = p_s1 + 1;
    const int  cnt1 = f1 ? max(p_e1 - st1, 0) : 0;
    const bool f2  = (p_s2 < S_) && (p_e2 < S_);
    const int  st2 = p_s2 + 1;
    const int  cnt2 = f2 ? max(p_e2 - st2, 0) : 0;

    const int   T    = 1 + cnt1 + cnt2;         // virtual row list: [cls, span1..., span2...]
    const float inv1 = cnt1 ? 1.0f / (float)cnt1 : 0.0f;
    const float inv2 = cnt2 ? 1.0f / (float)cnt2 : 0.0f;

    const int h0 = hthread * 4;
    const float* seqb = seq + (size_t)b * S_ * H_;

    const float4 w0 = *(const float4*)(W + h0);
    const float4 w1 = *(const float4*)(W + H_  + h0);
    const float4 w2 = *(const float4*)(W + 2*H_ + h0);

    float acc = 0.0f;
    #pragma unroll
    for (int i = 0; i < PER_SLICE; ++i) {
        const int  j    = slice + i * NSLICE;   // slice 0 gets j=0 (cls)
        const bool live = (j < T);
        const int  jj   = live ? j : 0;         // clamp dead rows to row 0 (valid memory)
        // decode virtual row jj -> (pos, w, scale); all wave-uniform scalars
        const bool isCls = (jj == 0);
        const bool isSp1 = (jj >= 1) && (jj <= cnt1);
        const int  pos   = isCls ? 0 : (isSp1 ? (st1 + jj - 1) : (st2 + jj - 1 - cnt1));
        const float4 w   = isCls ? w0 : (isSp1 ? w1 : w2);
        float scale      = isCls ? 1.0f : (isSp1 ? inv1 : inv2);
        if (!live) scale = 0.0f;

        const float4 v = *(const float4*)(seqb + (size_t)pos * H_ + h0);
        acc += (v.x * w.x + v.y * w.y + v.z * w.z + v.w * w.w) * scale;
    }

    // --- block reduction: 64-lane wave shuffle, then 16 wave partials ---
    #pragma unroll
    for (int off = 32; off > 0; off >>= 1)
        acc += __shfl_down(acc, off, 64);
    if ((tid & 63) == 0) wpart[tid >> 6] = acc;
    __syncthreads();
    if (tid == 0) {
        float s = 0.0f;
        #pragma unroll
        for (int wv = 0; wv < 16; ++wv) s += wpart[wv];
        out[b] = s + bias[0];
    }
}

extern "C" void kernel_launch(void* const* d_in, const int* in_sizes, int n_in,
                              void* d_out, int out_size, void* d_ws, size_t ws_size,
                              hipStream_t stream)
{
    const int*   ids  = (const int*)d_in[0];    // input_ids [B,S]
    // d_in[1] = attention_mask (unused by reference)
    const float* seq  = (const float*)d_in[2];  // sequence_output [B,S,H]
    const float* W    = (const float*)d_in[3];  // [3H,1]
    const float* bias = (const float*)d_in[4];  // [1]
    float* out = (float*)d_out;                 // [B]

    relcls_kernel<<<B_, 1024, 0, stream>>>(ids, seq, W, bias, out);
}